// Round 7
// baseline (391.956 us; speedup 1.0000x reference)
//
#include <hip/hip_runtime.h>
#include <stdint.h>

// ---------------------------------------------------------------------------
// GraphSAGE 2-layer: out = SAGE2(relu(SAGE1(x)))
// SAGE(x) = mean_agg(x@W_l.T) + b + x@W_r.T   (project-then-aggregate rewrite)
// R7: gemm A-operand loaded global->register directly in MFMA fragment layout
//     (no LDS, no barrier dependency for A); waves own 32x128 (no A dup);
//     B-only LDS dbuf (16 KB) async staging; XCD-aware mapping retained.
//     agg/final gather loops unrolled x2 for MLP.
// ---------------------------------------------------------------------------

#define D_IN  768
#define D_HID 256
#define N1    512   // concat(W1_l, W1_r) output width
#define KITERS (D_IN / 32)

typedef __attribute__((ext_vector_type(8))) short short8;
typedef __attribute__((ext_vector_type(4))) float f32x4;

__device__ __forceinline__ void async_copy16(const void* g, void* l) {
  __builtin_amdgcn_global_load_lds(
      (const __attribute__((address_space(1))) unsigned int*)g,
      (__attribute__((address_space(3))) unsigned int*)l,
      16, 0, 0);
}

__device__ __forceinline__ unsigned short f2bf(float f) {
  union { float f; unsigned u; } v; v.f = f;
  unsigned r = v.u + 0x7FFFu + ((v.u >> 16) & 1u);   // RNE
  return (unsigned short)(r >> 16);
}

__device__ __forceinline__ float bf2f(unsigned short b) {
  union { unsigned u; float f; } v; v.u = ((unsigned)b) << 16;
  return v.f;
}

// --------------------------- index handling --------------------------------

// convert + count, with block-local int64/int32 detection:
// if data is int64 (LE, values < 2^31), every odd 32-bit word is 0.
__global__ void cvtidx_k(const void* __restrict__ eidx,
                         int* __restrict__ src32, int* __restrict__ dst32,
                         int* __restrict__ counts, int E) {
  __shared__ int flag32;
  int tid = threadIdx.x;
  int i = blockIdx.x * 256 + tid;
  unsigned v = (i < E) ? ((const unsigned int*)eidx)[2 * (size_t)i + 1] : 0u;
  unsigned long long any = __ballot(v != 0u);
  if (tid == 0) flag32 = 0;
  __syncthreads();
  if ((tid & 63) == 0 && any) flag32 = 1;   // benign multi-writer (same value)
  __syncthreads();
  if (i >= E) return;
  int s, d;
  if (flag32) {  // int32 data
    const int* p = (const int*)eidx;
    s = p[i]; d = p[E + i];
  } else {       // int64 data
    const long long* p = (const long long*)eidx;
    s = (int)p[i]; d = (int)p[E + i];
  }
  src32[i] = s;
  dst32[i] = d;
  atomicAdd(&counts[d], 1);
}

// ----- hierarchical exclusive scan of counts[M] -> offs, cursor ------------
__global__ void scanA_k(const int* __restrict__ counts,
                        int* __restrict__ blockSums, int M) {
  __shared__ int ts[256];
  int b = blockIdx.x, t = threadIdx.x;
  int base = b * 1024 + t * 4;
  int s = 0;
#pragma unroll
  for (int k = 0; k < 4; k++) { int i = base + k; if (i < M) s += counts[i]; }
  ts[t] = s;
  __syncthreads();
  for (int off = 128; off > 0; off >>= 1) {
    if (t < off) ts[t] += ts[t + off];
    __syncthreads();
  }
  if (t == 0) blockSums[b] = ts[0];
}

// Each block wave-scans blockSums (nb<=64) itself, then local scan.
__global__ void scanC_k(const int* __restrict__ counts,
                        const int* __restrict__ bsums,
                        int* __restrict__ offs, int* __restrict__ cursor,
                        int M, int E, int nb) {
  __shared__ int ts[256];
  __shared__ int bofs;
  int b = blockIdx.x, t = threadIdx.x;
  if (t < 64) {
    int v = (t < nb) ? bsums[t] : 0;
    int orig = v;
#pragma unroll
    for (int off = 1; off < 64; off <<= 1) {
      int u = __shfl_up(v, off);
      if (t >= off) v += u;
    }
    if (t == b) bofs = v - orig;   // exclusive prefix of this block
  }
  int base = b * 1024 + t * 4;
  int v[4]; int s = 0;
#pragma unroll
  for (int k = 0; k < 4; k++) {
    int i = base + k;
    v[k] = (i < M) ? counts[i] : 0;
    s += v[k];
  }
  ts[t] = s;
  __syncthreads();
  for (int off = 1; off < 256; off <<= 1) {
    int x = (t >= off) ? ts[t - off] : 0;
    __syncthreads();
    ts[t] += x;
    __syncthreads();
  }
  int run = bofs + ts[t] - s;
#pragma unroll
  for (int k = 0; k < 4; k++) {
    int i = base + k;
    if (i < M) { offs[i] = run; cursor[i] = run; run += v[k]; }
  }
  if (b == 0 && t == 0) offs[M] = E;
}

__global__ void fill_k(const int* __restrict__ src, const int* __restrict__ dst,
                       int* __restrict__ cursor, int* __restrict__ csr, int E) {
  int i = blockIdx.x * 256 + threadIdx.x;
  if (i >= E) return;
  int pos = atomicAdd(&cursor[dst[i]], 1);
  csr[pos] = src[i];
}

// --------------------------- weight conversion -----------------------------

// wb rows 0..255 = W1_l, 256..511 = W1_r  (each [256,768])
__global__ void cvtw_k(const float* __restrict__ W1l, const float* __restrict__ W1r,
                       unsigned short* __restrict__ wb) {
  int idx = blockIdx.x * 256 + threadIdx.x;   // chunk of 8
  int total = N1 * (D_IN / 8);
  if (idx >= total) return;
  int row = idx / (D_IN / 8);
  int cpos = (idx % (D_IN / 8)) * 8;
  const float* p = (row < D_HID) ? (W1l + (size_t)row * D_IN + cpos)
                                 : (W1r + (size_t)(row - D_HID) * D_IN + cpos);
  float4 f0 = *(const float4*)p;
  float4 f1 = *(const float4*)(p + 4);
  short8 o;
  o[0] = (short)f2bf(f0.x); o[1] = (short)f2bf(f0.y);
  o[2] = (short)f2bf(f0.z); o[3] = (short)f2bf(f0.w);
  o[4] = (short)f2bf(f1.x); o[5] = (short)f2bf(f1.y);
  o[6] = (short)f2bf(f1.z); o[7] = (short)f2bf(f1.w);
  *(short8*)(wb + (size_t)idx * 8) = o;
}

// --------------------------- layer-1 GEMM ----------------------------------
// Cb[Mp, 512](bf16) = bf16(x[M, 768]) @ wb[512, 768]^T
// 128x128 tile, BK=32, 4 waves; wave w owns rows [w*32, w*32+32) x all 128
// cols: a-frags r=0,1 (global->reg direct, MFMA A layout = 2 x float4/lane),
// b-frags c=0..7 from LDS (dbuf, async, K-major conflict-free).
// One barrier/iter protects only the B buffer swap; A never touches LDS.
__global__ __launch_bounds__(256, 3) void gemm_k(
    const float* __restrict__ x,
    const unsigned short* __restrict__ wb,
    unsigned short* __restrict__ Cb, int M, int MT, int mtPerXcd) {
  __shared__ unsigned short Bs[2][128 * 32];   // 2 x 8 KB

  const int bid = blockIdx.x;
  const int xcd = bid & 7;
  const int j   = bid >> 3;
  const int mt  = xcd * mtPerXcd + (j >> 2);
  if (mt >= MT) return;
  const int m0 = mt * 128;
  const int n0 = (j & 3) * 128;

  const int tid  = threadIdx.x;
  const int lane = tid & 63;
  const int wid  = tid >> 6;
  const int l15  = lane & 15;
  const int quad = lane >> 4;

  // A row pointers (MFMA A-frag layout: lane reads row l15, k = quad*8..+7)
  const float* arp0 = x + (size_t)min(m0 + wid * 32      + l15, M - 1) * D_IN + quad * 8;
  const float* arp1 = x + (size_t)min(m0 + wid * 32 + 16 + l15, M - 1) * D_IN + quad * 8;

  // B staging: chunks tid and tid+256; K-major segments (conflict-free)
  const int brow = (tid >> 6) * 16 + (tid & 15);
  const int bcg  = (tid >> 4) & 3;
  const unsigned short* bgp0 = wb + (size_t)(n0 + brow) * D_IN + bcg * 8;
  const unsigned short* bgp1 = wb + (size_t)(n0 + brow + 64) * D_IN + bcg * 8;
  const int boff0 = tid * 8;
  const int boff1 = (tid + 256) * 8;

  f32x4 acc[2][8];
#pragma unroll
  for (int r = 0; r < 2; r++)
#pragma unroll
    for (int c = 0; c < 8; c++) acc[r][c] = (f32x4)0.0f;

  // prologue: B(0) async, A(0) regs
  async_copy16(bgp0, &Bs[0][boff0]);
  async_copy16(bgp1, &Bs[0][boff1]);
  float4 an00 = *(const float4*)(arp0);
  float4 an01 = *(const float4*)(arp0 + 4);
  float4 an10 = *(const float4*)(arp1);
  float4 an11 = *(const float4*)(arp1 + 4);

  for (int it = 0; it < KITERS; ++it) {
    const int p = it & 1;
    __syncthreads();   // waves done with Bs[p^1]; drains B(it) async + A(it)
                       // loads (both issued LAST iter -> one full iter of slack)
    if (it + 1 < KITERS) {
      const int kn = (it + 1) * 32;
      async_copy16(bgp0 + kn, &Bs[p ^ 1][boff0]);
      async_copy16(bgp1 + kn, &Bs[p ^ 1][boff1]);
    }
    // cvt A(it) regs -> MFMA frags
    short8 a0, a1;
    a0[0] = (short)f2bf(an00.x); a0[1] = (short)f2bf(an00.y);
    a0[2] = (short)f2bf(an00.z); a0[3] = (short)f2bf(an00.w);
    a0[4] = (short)f2bf(an01.x); a0[5] = (short)f2bf(an01.y);
    a0[6] = (short)f2bf(an01.z); a0[7] = (short)f2bf(an01.w);
    a1[0] = (short)f2bf(an10.x); a1[1] = (short)f2bf(an10.y);
    a1[2] = (short)f2bf(an10.z); a1[3] = (short)f2bf(an10.w);
    a1[4] = (short)f2bf(an11.x); a1[5] = (short)f2bf(an11.y);
    a1[6] = (short)f2bf(an11.z); a1[7] = (short)f2bf(an11.w);
    if (it + 1 < KITERS) {
      const int kp = (it + 1) * 32;
      an00 = *(const float4*)(arp0 + kp);
      an01 = *(const float4*)(arp0 + kp + 4);
      an10 = *(const float4*)(arp1 + kp);
      an11 = *(const float4*)(arp1 + kp + 4);
    }

    short8 b[8];
#pragma unroll
    for (int c = 0; c < 8; c++)
      b[c] = *(const short8*)&Bs[p][c * 512 + quad * 128 + l15 * 8];
#pragma unroll
    for (int c = 0; c < 8; c++) {
      acc[0][c] = __builtin_amdgcn_mfma_f32_16x16x32_bf16(a0, b[c], acc[0][c], 0, 0, 0);
      acc[1][c] = __builtin_amdgcn_mfma_f32_16x16x32_bf16(a1, b[c], acc[1][c], 0, 0, 0);
    }
  }

  // epilogue: C/D layout col=lane&15, row=(lane>>4)*4+reg; store bf16
  const int crow0 = m0 + wid * 32;
#pragma unroll
  for (int r = 0; r < 2; r++)
#pragma unroll
    for (int c = 0; c < 8; c++) {
      int col = n0 + c * 16 + l15;
#pragma unroll
      for (int reg = 0; reg < 4; reg++) {
        int row = crow0 + r * 16 + quad * 4 + reg;
        Cb[(size_t)row * N1 + col] = f2bf(acc[r][c][reg]);
      }
    }
}

// --------------------- fused aggregate + epilogue + layer-2 ----------------
// h[c] = relu( mean_{j in N(i)} Cb[j][c] + b1[c] + Cb[i][256+c] )  (registers)
// rs[i] = { h@W2_l[0], h@W2_l[1], h@W2_r[0], h@W2_r[1] }
// one wave per node; gather loop unrolled x2 for MLP
__global__ void agg_l2_k(const unsigned short* __restrict__ Cb,
                         const int* __restrict__ offs, const int* __restrict__ csr,
                         const float* __restrict__ b1,
                         const float* __restrict__ W2l, const float* __restrict__ W2r,
                         float4* __restrict__ rs, int M) {
  int tid = threadIdx.x;
  int lane = tid & 63;
  int wid = tid >> 6;
  int i = blockIdx.x * 4 + wid;
  if (i >= M) return;
  int c = lane * 4;
  float4 bv  = *(const float4*)(b1 + c);
  float4 wl0 = *(const float4*)(W2l + c);
  float4 wl1 = *(const float4*)(W2l + D_HID + c);
  float4 wr0 = *(const float4*)(W2r + c);
  float4 wr1 = *(const float4*)(W2r + D_HID + c);
  int s = offs[i], e = offs[i + 1];
  float ax = 0.f, ay = 0.f, az = 0.f, aw = 0.f;
  int t = s;
  for (; t + 2 <= e; t += 2) {
    int j0 = csr[t], j1 = csr[t + 1];
    ushort4 v0 = *(const ushort4*)(Cb + (size_t)j0 * N1 + c);
    ushort4 v1 = *(const ushort4*)(Cb + (size_t)j1 * N1 + c);
    ax += bf2f(v0.x) + bf2f(v1.x); ay += bf2f(v0.y) + bf2f(v1.y);
    az += bf2f(v0.z) + bf2f(v1.z); aw += bf2f(v0.w) + bf2f(v1.w);
  }
  if (t < e) {
    int j0 = csr[t];
    ushort4 v0 = *(const ushort4*)(Cb + (size_t)j0 * N1 + c);
    ax += bf2f(v0.x); ay += bf2f(v0.y); az += bf2f(v0.z); aw += bf2f(v0.w);
  }
  float inv = 1.0f / fmaxf((float)(e - s), 1.0f);
  ushort4 q = *(const ushort4*)(Cb + (size_t)i * N1 + D_HID + c);
  float h0 = fmaxf(ax * inv + bv.x + bf2f(q.x), 0.0f);
  float h1 = fmaxf(ay * inv + bv.y + bf2f(q.y), 0.0f);
  float h2 = fmaxf(az * inv + bv.z + bf2f(q.z), 0.0f);
  float h3 = fmaxf(aw * inv + bv.w + bf2f(q.w), 0.0f);
  float r0 = h0 * wl0.x + h1 * wl0.y + h2 * wl0.z + h3 * wl0.w;
  float r1 = h0 * wl1.x + h1 * wl1.y + h2 * wl1.z + h3 * wl1.w;
  float s0 = h0 * wr0.x + h1 * wr0.y + h2 * wr0.z + h3 * wr0.w;
  float s1 = h0 * wr1.x + h1 * wr1.y + h2 * wr1.z + h3 * wr1.w;
#pragma unroll
  for (int off = 32; off > 0; off >>= 1) {
    r0 += __shfl_xor(r0, off);
    r1 += __shfl_xor(r1, off);
    s0 += __shfl_xor(s0, off);
    s1 += __shfl_xor(s1, off);
  }
  if (lane == 0) rs[i] = make_float4(r0, r1, s0, s1);
}

// --------------------------- final -----------------------------------------
// out[i][j] = mean_{k in N(i)} rs[k][j] + b2[j] + rs[i][2+j]
__global__ void final_k(const float4* __restrict__ rs, const int* __restrict__ offs,
                        const int* __restrict__ csr, const float* __restrict__ b2,
                        float* __restrict__ out, int M) {
  int i = blockIdx.x * 256 + threadIdx.x;
  if (i >= M) return;
  int s = offs[i], e = offs[i + 1];
  float a0 = 0.0f, a1 = 0.0f;
  int t = s;
  for (; t + 2 <= e; t += 2) {
    float4 v0 = rs[csr[t]];
    float4 v1 = rs[csr[t + 1]];
    a0 += v0.x + v1.x; a1 += v0.y + v1.y;
  }
  if (t < e) {
    float4 v0 = rs[csr[t]];
    a0 += v0.x; a1 += v0.y;
  }
  float inv = 1.0f / fmaxf((float)(e - s), 1.0f);
  float4 me = rs[i];
  out[2 * i + 0] = a0 * inv + b2[0] + me.z;
  out[2 * i + 1] = a1 * inv + b2[1] + me.w;
}

// ---------------------------------------------------------------------------

extern "C" void kernel_launch(void* const* d_in, const int* in_sizes, int n_in,
                              void* d_out, int out_size, void* d_ws, size_t ws_size,
                              hipStream_t stream) {
  const float* x   = (const float*)d_in[0];
  const void*  eix = d_in[1];
  const float* W1l = (const float*)d_in[2];
  const float* b1  = (const float*)d_in[3];
  const float* W1r = (const float*)d_in[4];
  const float* W2l = (const float*)d_in[5];
  const float* b2  = (const float*)d_in[6];
  const float* W2r = (const float*)d_in[7];
  float* out = (float*)d_out;

  const int M  = in_sizes[0] / D_IN;       // 50000
  const int E  = in_sizes[1] / 2;          // 250000
  const int Mp = ((M + 127) / 128) * 128;  // 50048
  const int nb = (M + 1023) / 1024;        // scan blocks (<=64)
  const int MT = Mp / 128;                 // 391 m-tiles
  const int mtPerXcd = (MT + 7) / 8;       // 49
  const int gemmBlocks = 8 * mtPerXcd * 4; // 1568 (some return early)

  // workspace layout (256B aligned slots)
  char* ws = (char*)d_ws;
  size_t off = 0;
  auto alloc = [&](size_t b) { size_t o = off; off += (b + 255) & ~(size_t)255; return o; };
  size_t oCounts = alloc((size_t)M * 4);
  size_t zeroBytes = (size_t)M * 4;        // counts
  size_t oOffs   = alloc((size_t)(M + 1) * 4);
  size_t oCursor = alloc((size_t)M * 4);
  size_t oCsr    = alloc((size_t)E * 4);
  size_t oSrc    = alloc((size_t)E * 4);
  size_t oDst    = alloc((size_t)E * 4);
  size_t oBSums  = alloc(64 * 4);
  size_t oWb     = alloc((size_t)N1 * D_IN * 2);
  size_t oC      = alloc((size_t)Mp * N1 * 2);     // bf16
  size_t oRs     = alloc((size_t)M * 16);
  (void)ws_size; (void)n_in; (void)out_size;

  int* counts = (int*)(ws + oCounts);
  int* offs   = (int*)(ws + oOffs);
  int* cursor = (int*)(ws + oCursor);
  int* csr    = (int*)(ws + oCsr);
  int* src32  = (int*)(ws + oSrc);
  int* dst32  = (int*)(ws + oDst);
  int* bsums  = (int*)(ws + oBSums);
  unsigned short* wb = (unsigned short*)(ws + oWb);
  unsigned short* Cb = (unsigned short*)(ws + oC);
  float4* rs = (float4*)(ws + oRs);

  hipMemsetAsync(counts, 0, zeroBytes, stream);

  int gE = (E + 255) / 256;
  cvtidx_k<<<gE, 256, 0, stream>>>(eix, src32, dst32, counts, E);
  scanA_k<<<nb, 256, 0, stream>>>(counts, bsums, M);
  scanC_k<<<nb, 256, 0, stream>>>(counts, bsums, offs, cursor, M, E, nb);
  fill_k<<<gE, 256, 0, stream>>>(src32, dst32, cursor, csr, E);

  int gW = (N1 * (D_IN / 8) + 255) / 256;
  cvtw_k<<<gW, 256, 0, stream>>>(W1l, W1r, wb);

  gemm_k<<<gemmBlocks, 256, 0, stream>>>(x, wb, Cb, M, MT, mtPerXcd);

  agg_l2_k<<<(M + 3) / 4, 256, 0, stream>>>(Cb, offs, csr, b1, W2l, W2r, rs, M);
  final_k<<<(M + 255) / 256, 256, 0, stream>>>(rs, offs, csr, b2, out, M);
}